// Round 2
// baseline (310.177 us; speedup 1.0000x reference)
//
#include <hip/hip_runtime.h>
#include <hip/hip_bf16.h>

// Problem constants (from reference)
#define D_H     512
#define D_MODEL 2048
#define B_      4
#define T_      4096
// T_*D_MODEL = 2^23  (for the >>23 / &2047 index tricks below)

// out[b][j] += sum_{k in chunk} x[b][k] * W[k][j]
// x: (B x K) fp32; W: (K x N) fp32 row-major; out: (B x N) fp32 (pre-zeroed)
__global__ void gemv_splitk(const float* __restrict__ x,
                            const float* __restrict__ W,
                            float* __restrict__ out,
                            int K, int N, int kchunk) {
    int j  = blockIdx.x * blockDim.x + threadIdx.x;   // output column
    int b  = blockIdx.y;                              // batch row
    int k0 = blockIdx.z * kchunk;                     // K-chunk start
    extern __shared__ float xs[];
    for (int k = threadIdx.x; k < kchunk; k += blockDim.x)
        xs[k] = x[b * K + k0 + k];
    __syncthreads();
    if (j >= N) return;
    const float* Wp = W + (long)k0 * N + j;
    float acc = 0.f;
#pragma unroll 8
    for (int k = 0; k < kchunk; ++k)
        acc = fmaf(xs[k], Wp[(long)k * N], acc);
    atomicAdd(&out[b * N + j], acc);
}

// out[b,t,:] = lh[b,t,:] + sigmoid(gate) * r[b,:]
// Processes 4 fp32 elements (16 B) per thread.
__global__ void broadcast_add(const float4* __restrict__ lh,
                              const float* __restrict__ r,
                              const float* __restrict__ gate,
                              float4* __restrict__ out) {
    const long CHUNKS = (long)B_ * T_ * D_MODEL / 4;
    long i = (long)blockIdx.x * blockDim.x + threadIdx.x;
    if (i >= CHUNKS) return;

    float g = gate[0];
    float s = 1.0f / (1.0f + __expf(-g));

    long e0 = i * 4;
    int  b  = (int)(e0 >> 23);             // / (T_*D_MODEL)
    int  d  = (int)(e0 & (D_MODEL - 1));   // col within row (4-aligned)

    float4 rv = *reinterpret_cast<const float4*>(r + b * D_MODEL + d);
    float4 v  = lh[i];

    float4 o;
    o.x = fmaf(s, rv.x, v.x);
    o.y = fmaf(s, rv.y, v.y);
    o.z = fmaf(s, rv.z, v.z);
    o.w = fmaf(s, rv.w, v.w);
    out[i] = o;
}

extern "C" void kernel_launch(void* const* d_in, const int* in_sizes, int n_in,
                              void* d_out, int out_size, void* d_ws, size_t ws_size,
                              hipStream_t stream) {
    const float* lh    = (const float*)d_in[0];
    const float* zH    = (const float*)d_in[1];
    const float* W_mem = (const float*)d_in[2];
    // d_in[3] = W_q, d_in[4] = W_k  -- provably unused: softmax over a
    // length-1 axis is identically 1, so output is independent of Q and K.
    const float* W_v   = (const float*)d_in[5];
    const float* W_o   = (const float*)d_in[6];
    const float* gate  = (const float*)d_in[7];
    float* out = (float*)d_out;

    // fp32 workspace: mem(B x D), V(B x D), r(B x D)
    float* mem = (float*)d_ws;
    float* V   = mem + B_ * D_MODEL;
    float* r   = V   + B_ * D_MODEL;
    hipMemsetAsync(d_ws, 0, (size_t)3 * B_ * D_MODEL * sizeof(float), stream);

    dim3 blk(256);

    // Stage 1: mem = zH @ W_mem   (K = 512, split-K by 8 -> chunk 64)
    {
        dim3 grd(D_MODEL / 256, B_, 8);
        gemv_splitk<<<grd, blk, 64 * sizeof(float), stream>>>(
            zH, W_mem, mem, D_H, D_MODEL, 64);
    }
    // Stage 2: V = mem @ W_v      (K = 2048, split-K by 8 -> chunk 256)
    {
        dim3 grd(D_MODEL / 256, B_, 8);
        gemv_splitk<<<grd, blk, 256 * sizeof(float), stream>>>(
            mem, W_v, V, D_MODEL, D_MODEL, 256);
    }
    // Stage 3: r = V @ W_o
    {
        dim3 grd(D_MODEL / 256, B_, 8);
        gemv_splitk<<<grd, blk, 256 * sizeof(float), stream>>>(
            V, W_o, r, D_MODEL, D_MODEL, 256);
    }
    // Stage 4: out = lh + sigmoid(gate) * r  (broadcast over T)
    {
        long chunks = (long)B_ * T_ * D_MODEL / 4;
        dim3 grd((unsigned)((chunks + 255) / 256));
        broadcast_add<<<grd, blk, 0, stream>>>(
            (const float4*)lh, r, gate, (float4*)out);
    }
}

// Round 4
// 282.104 us; speedup vs baseline: 1.0995x; 1.0995x over previous
//
#include <hip/hip_runtime.h>
#include <hip/hip_bf16.h>

// Problem constants (from reference)
#define D_H     512
#define D_MODEL 2048
#define B_      4
#define T_      4096
// T_*D_MODEL = 2^23  (for the >>23 / &2047 index tricks below)

// Native clang vector (works with __builtin_nontemporal_*; same layout as float4)
typedef float vfloat4 __attribute__((ext_vector_type(4)));

// out[b][j] += sum_{k in slice} x[b][k] * W[k][j]   for all b in [0,4)
// One W element is loaded ONCE and FMA'd into 4 batch accumulators.
// x: (4 x K) fp32; W: (K x N) fp32 row-major; out: (4 x N) fp32 (pre-zeroed)
template <int KCHUNK>
__global__ void gemv4_splitk(const float* __restrict__ x,
                             const float* __restrict__ W,
                             float* __restrict__ out,
                             int K, int N) {
    __shared__ float xs[4][KCHUNK];
    const int tid = threadIdx.x;
    const int j   = blockIdx.x * blockDim.x + tid;    // output column
    const int k0  = blockIdx.y * KCHUNK;              // K-slice start

    for (int i = tid; i < 4 * KCHUNK; i += blockDim.x) {
        int b = i / KCHUNK, k = i - b * KCHUNK;
        xs[b][k] = x[b * K + k0 + k];
    }
    __syncthreads();

    float a0 = 0.f, a1 = 0.f, a2 = 0.f, a3 = 0.f;
    const float* Wp = W + (long)k0 * N + j;
#pragma unroll 8
    for (int k = 0; k < KCHUNK; ++k) {
        float w = Wp[(long)k * N];                    // wave reads 256B contiguous
        a0 = fmaf(xs[0][k], w, a0);                   // xs[b][k]: same addr all lanes -> broadcast
        a1 = fmaf(xs[1][k], w, a1);
        a2 = fmaf(xs[2][k], w, a2);
        a3 = fmaf(xs[3][k], w, a3);
    }
    atomicAdd(&out[0 * N + j], a0);
    atomicAdd(&out[1 * N + j], a1);
    atomicAdd(&out[2 * N + j], a2);
    atomicAdd(&out[3 * N + j], a3);
}

// out[b,t,:] = lh[b,t,:] + sigmoid(gate) * r[b,:]
// 4 fp32 (16 B) per thread; lh/out are zero-reuse streams -> nontemporal.
__global__ void broadcast_add(const vfloat4* __restrict__ lh,
                              const float* __restrict__ r,
                              const float* __restrict__ gate,
                              vfloat4* __restrict__ out) {
    long i = (long)blockIdx.x * blockDim.x + threadIdx.x;

    float g = gate[0];
    float s = 1.0f / (1.0f + __expf(-g));

    long e0 = i * 4;
    int  b  = (int)(e0 >> 23);             // / (T_*D_MODEL)
    int  d  = (int)(e0 & (D_MODEL - 1));   // col within row (4-aligned)

    vfloat4 rv = *reinterpret_cast<const vfloat4*>(r + b * D_MODEL + d);  // L2-resident
    vfloat4 v  = __builtin_nontemporal_load(lh + i);

    vfloat4 o;
    o.x = fmaf(s, rv.x, v.x);
    o.y = fmaf(s, rv.y, v.y);
    o.z = fmaf(s, rv.z, v.z);
    o.w = fmaf(s, rv.w, v.w);
    __builtin_nontemporal_store(o, out + i);
}

extern "C" void kernel_launch(void* const* d_in, const int* in_sizes, int n_in,
                              void* d_out, int out_size, void* d_ws, size_t ws_size,
                              hipStream_t stream) {
    const float* lh    = (const float*)d_in[0];
    const float* zH    = (const float*)d_in[1];
    const float* W_mem = (const float*)d_in[2];
    // d_in[3] = W_q, d_in[4] = W_k  -- provably unused: softmax over a
    // length-1 axis is identically 1, so output is independent of Q and K.
    const float* W_v   = (const float*)d_in[5];
    const float* W_o   = (const float*)d_in[6];
    const float* gate  = (const float*)d_in[7];
    float* out = (float*)d_out;

    // fp32 workspace: mem(4 x D), V(4 x D), r(4 x D)
    float* mem = (float*)d_ws;
    float* V   = mem + B_ * D_MODEL;
    float* r   = V   + B_ * D_MODEL;
    (void)hipMemsetAsync(d_ws, 0, (size_t)3 * B_ * D_MODEL * sizeof(float), stream);

    dim3 blk(256);

    // Stage 1: mem = zH @ W_mem   (K=512,  32 slices x 16)
    {
        dim3 grd(D_MODEL / 256, 32);
        gemv4_splitk<16><<<grd, blk, 0, stream>>>(zH, W_mem, mem, D_H, D_MODEL);
    }
    // Stage 2: V = mem @ W_v      (K=2048, 32 slices x 64)
    {
        dim3 grd(D_MODEL / 256, 32);
        gemv4_splitk<64><<<grd, blk, 0, stream>>>(mem, W_v, V, D_MODEL, D_MODEL);
    }
    // Stage 3: r = V @ W_o        (K=2048, 32 slices x 64)
    {
        dim3 grd(D_MODEL / 256, 32);
        gemv4_splitk<64><<<grd, blk, 0, stream>>>(V, W_o, r, D_MODEL, D_MODEL);
    }
    // Stage 4: out = lh + sigmoid(gate) * r  (broadcast over T)
    {
        long chunks = (long)B_ * T_ * D_MODEL / 4;   // 8,388,608
        dim3 grd((unsigned)(chunks / 256));          // exact multiple
        broadcast_add<<<grd, blk, 0, stream>>>(
            (const vfloat4*)lh, r, gate, (vfloat4*)out);
    }
}